// Round 15
// baseline (136.537 us; speedup 1.0000x reference)
//
#include <hip/hip_runtime.h>
#include <hip/hip_bf16.h>
#include <stdint.h>

// Problem constants (fixed by reference spec; dtypes f32/int32 verified over
// rounds 3-14 — bit-stable outputs; bounds-clamps retained as the safety net)
#define N_NODES   10000
#define D_FEAT    256
#define E_EDGES   320000
#define ROW_WORDS 313     // ceil(10000/32) bitmap words per row
#define ROW_STRIDE 320    // fallback plan: padded words per bitmap row
#define LIST_CAP  1024    // fallback plan: per-wave neighbor list capacity

// Compact bucketed-CSR build (r13-proven fill; r15 reverts r14's slot layout:
// slots tripled the CSR scan volume to save a 1 us memset — bad trade).
#define NB     250        // buckets
#define RPB    40         // rows per bucket (250*40 = 10000 exactly)
#define B_CAP  8192       // entries per bucket; mean 5120, sigma ~71
#define NBLK_E 313        // edge blocks in fill_buckets ((320000+1023)/1024)
#define NBLK_W 64         // wcast blocks appended to fill_buckets
#define RPC    10         // rows per CSR block (1000 quarter-bucket blocks)
#define NBLK_C 1000       // csr blocks in csr_gemm
#define NBLK_G 625        // gemm blocks appended in csr_gemm (16 rows each)
#define COLSTR 128        // fixed col stride per row (max deg ~100 << 128)

#define LDSTR 264         // f16 LDS row stride for gemm (256 + 8 pad)

typedef __attribute__((ext_vector_type(4))) float float4v;   // 4 x f32
typedef _Float16 half8  __attribute__((ext_vector_type(8))); // 8 x f16 (4 VGPR)
typedef _Float16 half4v __attribute__((ext_vector_type(4))); // 4 x f16

__device__ __forceinline__ float h2f_lo(uint32_t u) {
    union { uint32_t u; _Float16 h[2]; } v; v.u = u; return (float)v.h[0];
}
__device__ __forceinline__ float h2f_hi(uint32_t u) {
    union { uint32_t u; _Float16 h[2]; } v; v.u = u; return (float)v.h[1];
}

// ===========================================================================
// PRIMARY PLAN (3 dispatches + 1 KB memset):
//   K1 fill_buckets : LDS counting sort -> compact per-bucket runs
//                     (250 LDS-aggregated cursor atomics/block) + f16 W^T
//   K2 csr_gemm     : [0,1000) quarter-bucket LDS bitmap dedup -> deg/dinv
//                     -> fixed-stride CSR; [1000,1625) yw = f16(x @ W) MFMA
//   K3 spmm_out     : out_i = dinv_i*(sum dinv_j*yw_j + dinv_i*yw_i)
// r11 lesson kept: wave-per-row in the latency-bound gather.
// ===========================================================================

// ---------------------------------------------------------------------------
// K1: blocks [0,313): counting-sorted bucket fill (r13-proven — coalesced
// runs, cursor atomics are 250/block and LDS-aggregated).
//     blocks [313,377): wT[n][k] = f16(W[k][n]) (fused, r12-proven).
// ---------------------------------------------------------------------------
__global__ void __launch_bounds__(1024)
fill_buckets(const int* __restrict__ ei, uint32_t* __restrict__ bucketbuf,
             uint32_t* __restrict__ cursors,
             const float* __restrict__ w, _Float16* __restrict__ wt) {
    __shared__ uint32_t hist[256];
    __shared__ uint32_t lofs[256];     // inclusive scan of hist
    __shared__ uint32_t base_s[256];
    __shared__ uint32_t stage[2048];   // also reused as f32[1024] by wcast
    __shared__ uint16_t sbkt[2048];
    int t = threadIdx.x;

    if (blockIdx.x >= NBLK_E) {        // ---- fused wcast blocks ----
        int kb = (blockIdx.x - NBLK_E) * 4;
        int k = kb + (t >> 8), n = t & 255;
        float* st = (float*)stage;     // 4 KB staging
        st[(n << 2) | (t >> 8)] = w[(size_t)k * D_FEAT + n];
        __syncthreads();
        if (t < 256) {
            half4v o = { (_Float16)st[t * 4 + 0], (_Float16)st[t * 4 + 1],
                         (_Float16)st[t * 4 + 2], (_Float16)st[t * 4 + 3] };
            *(half4v*)&wt[(size_t)t * D_FEAT + kb] = o;
        }
        return;
    }

    if (t < 256) hist[t] = 0;
    __syncthreads();
    int e = blockIdx.x * 1024 + t;
    int b0 = -1, b1 = -1; uint32_t ent0 = 0, ent1 = 0, s0 = 0, s1 = 0;
    if (e < E_EDGES) {
        int s = ei[e], d = ei[E_EDGES + e];
        if ((uint32_t)s < N_NODES && (uint32_t)d < N_NODES) {
            b0 = s / RPB; ent0 = ((uint32_t)(s - b0 * RPB) << 14) | (uint32_t)d;
            b1 = d / RPB; ent1 = ((uint32_t)(d - b1 * RPB) << 14) | (uint32_t)s;
            s0 = atomicAdd(&hist[b0], 1u);    // LDS atomics
            s1 = atomicAdd(&hist[b1], 1u);
        }
    }
    __syncthreads();
    if (t < 256) lofs[t] = hist[t];
    __syncthreads();
    for (int d = 1; d < 256; d <<= 1) {              // Hillis-Steele inclusive
        uint32_t v = 0;
        if (t < 256 && t >= d) v = lofs[t - d];
        __syncthreads();
        if (t < 256) lofs[t] += v;
        __syncthreads();
    }
    if (t < 256) base_s[t] = hist[t] ? atomicAdd(&cursors[t], hist[t]) : 0u;
    if (b0 >= 0) {                     // stage sorted by bucket
        uint32_t p0 = lofs[b0] - hist[b0] + s0;
        stage[p0] = ent0; sbkt[p0] = (uint16_t)b0;
        uint32_t p1 = lofs[b1] - hist[b1] + s1;
        stage[p1] = ent1; sbkt[p1] = (uint16_t)b1;
    }
    __syncthreads();
    uint32_t total = lofs[255];
    for (uint32_t idx = t; idx < total; idx += 1024) {
        uint32_t b = sbkt[idx];
        uint32_t pos = base_s[b] + (idx - (lofs[b] - hist[b]));
        if (pos < B_CAP) bucketbuf[(size_t)b * B_CAP + pos] = stage[idx];
    }
}

// ---------------------------------------------------------------------------
// K2: heterogeneous grid.
//  blocks [0,1000): quarter-bucket CSR build — scan cnt[b] compact entries
//    (all lanes useful, ~5 iterations), LDS bitmap dedup (12.5 KB), per-row
//    popc -> deg/dinv, expand to col[gi*128 ...] (fixed stride, no atomics).
//  blocks [1000,1625): yw[16 rows] = f16(x @ W): x-tile f16 in LDS, 16 waves
//    x 1 col-tile, mfma_f32_16x16x32_f16 (m89/m91 layout, r10-verified).
// ---------------------------------------------------------------------------
__global__ void __launch_bounds__(1024)
csr_gemm(const uint32_t* __restrict__ bucketbuf, const uint32_t* __restrict__ cursors,
         uint32_t* __restrict__ row_deg, float* __restrict__ dinv,
         uint32_t* __restrict__ col,
         const float* __restrict__ x, const _Float16* __restrict__ wt,
         _Float16* __restrict__ yw) {
    __shared__ __align__(16) uint32_t smem[RPC * ROW_WORDS];   // 12,520 B
    int t = threadIdx.x;

    if (blockIdx.x >= NBLK_C) {        // ---- gemm blocks ----
        _Float16* a_lds = (_Float16*)smem;             // 16*264 f16 = 8448 B
        int r0 = (blockIdx.x - NBLK_C) * 16;
        int row = t >> 6, c4 = (t & 63) * 4;           // 1024 thr = 16x64 f4
        float4v xv = *(const float4v*)(x + (size_t)(r0 + row) * D_FEAT + c4);
        half4v h = { (_Float16)xv[0], (_Float16)xv[1],
                     (_Float16)xv[2], (_Float16)xv[3] };
        *(half4v*)&a_lds[row * LDSTR + c4] = h;
        __syncthreads();
        int wv = t >> 6, lane = t & 63;
        int quad = lane >> 4, r = lane & 15;
        int ct = wv;                                   // 16 waves = 16 col tiles
        const _Float16* pb = wt + (size_t)(ct * 16 + r) * D_FEAT + quad * 8;
        float4v acc = {0.f, 0.f, 0.f, 0.f};
        #pragma unroll
        for (int kk = 0; kk < D_FEAT; kk += 32) {
            half8 a = *(const half8*)&a_lds[r * LDSTR + kk + quad * 8];
            half8 b = *(const half8*)(pb + kk);
            acc = __builtin_amdgcn_mfma_f32_16x16x32_f16(a, b, acc, 0, 0, 0);
        }
        int colg = ct * 16 + r;
        #pragma unroll
        for (int u = 0; u < 4; u++)
            yw[(size_t)(r0 + quad * 4 + u) * D_FEAT + colg] = (_Float16)acc[u];
        return;
    }

    // ---- csr blocks ----
    uint32_t* bm = smem;                               // 10*313 words
    int b   = blockIdx.x >> 2;                         // bucket
    int lr0 = (blockIdx.x & 3) * RPC;                  // local-row window
    for (int i = t; i < RPC * ROW_WORDS; i += 1024) bm[i] = 0;
    __syncthreads();
    uint32_t cnt = min(cursors[b], (uint32_t)B_CAP);
    const uint32_t* bb = bucketbuf + (size_t)b * B_CAP;
    for (uint32_t i = t; i < cnt; i += 1024) {
        uint32_t ent = bb[i];
        uint32_t lr = (ent >> 14) - (uint32_t)lr0;
        if (lr < RPC) {
            uint32_t d = ent & 0x3FFFu;
            atomicOr(&bm[lr * ROW_WORDS + (d >> 5)], 1u << (d & 31));
        }
    }
    __syncthreads();
    int wv = t >> 6, lane = t & 63;                    // 16 waves, 10 rows
    for (int r = wv; r < RPC; r += 16) {
        int gi = b * RPB + lr0 + r;
        uint32_t wb[5]; int tot = 0;
        #pragma unroll
        for (int k = 0; k < 5; k++) {
            int w = lane + 64 * k;
            uint32_t v = (w < ROW_WORDS) ? bm[r * ROW_WORDS + w] : 0u;
            wb[k] = v; tot += __popc(v);
        }
        int incl = tot;
        #pragma unroll
        for (int off = 1; off < 64; off <<= 1) {
            int v = __shfl_up(incl, off, 64);
            if (lane >= off) incl += v;
        }
        uint32_t total = (uint32_t)__shfl(incl, 63, 64);
        if (lane == 0) {
            row_deg[gi] = min(total, (uint32_t)COLSTR);
            dinv[gi]    = 1.0f / sqrtf((float)(total + 1u));  // +1 = the eye
        }
        uint32_t p = (uint32_t)(incl - tot);
        #pragma unroll
        for (int k = 0; k < 5; k++) {
            uint32_t bits = wb[k];
            uint32_t cbase = (uint32_t)(lane + 64 * k) << 5;
            while (bits) {
                if (p < COLSTR)
                    col[(size_t)gi * COLSTR + p] = cbase + (uint32_t)__builtin_ctz(bits);
                p++;
                bits &= bits - 1;
            }
        }
    }
}

// ---------------------------------------------------------------------------
// K3: final gather straight into d_out (f32). Wave-per-row (10000 waves),
// 8 independent gather streams (r13-proven). Per-j dinv multiply (yw is the
// UNSCALED X@W — reassociation: out = S·(X·W)).
// ---------------------------------------------------------------------------
__global__ void __launch_bounds__(256)
spmm_out(const uint32_t* __restrict__ row_deg, const float* __restrict__ dinv,
         const uint32_t* __restrict__ col, const _Float16* __restrict__ ywp,
         float* __restrict__ out) {
    const uint16_t* yw = (const uint16_t*)ywp;
    int wv = threadIdx.x >> 6, lane = threadIdx.x & 63;
    int i = blockIdx.x * 4 + wv;
    uint32_t base = (uint32_t)i * COLSTR;
    uint32_t deg = min(row_deg[i], (uint32_t)COLSTR);
    float di = dinv[i];
    float4v z = {0.f, 0.f, 0.f, 0.f};
    float4v a0 = z, a1 = z, a2 = z, a3 = z, a4 = z, a5 = z, a6 = z, a7 = z;
    size_t ch = (size_t)lane * 4;
    uint32_t t8 = deg & ~7u;
    uint32_t t = 0;
    for (; t < t8; t += 8) {
        uint4 jva = *(const uint4*)&col[base + t];       // wave-uniform bcast
        uint4 jvb = *(const uint4*)&col[base + t + 4];
        float d0 = dinv[jva.x], d1 = dinv[jva.y], d2 = dinv[jva.z], d3 = dinv[jva.w];
        float d4 = dinv[jvb.x], d5 = dinv[jvb.y], d6 = dinv[jvb.z], d7 = dinv[jvb.w];
        uint2 g0 = *(const uint2*)(yw + (size_t)jva.x * D_FEAT + ch);
        uint2 g1 = *(const uint2*)(yw + (size_t)jva.y * D_FEAT + ch);
        uint2 g2 = *(const uint2*)(yw + (size_t)jva.z * D_FEAT + ch);
        uint2 g3 = *(const uint2*)(yw + (size_t)jva.w * D_FEAT + ch);
        uint2 g4 = *(const uint2*)(yw + (size_t)jvb.x * D_FEAT + ch);
        uint2 g5 = *(const uint2*)(yw + (size_t)jvb.y * D_FEAT + ch);
        uint2 g6 = *(const uint2*)(yw + (size_t)jvb.z * D_FEAT + ch);
        uint2 g7 = *(const uint2*)(yw + (size_t)jvb.w * D_FEAT + ch);
        a0[0] += d0 * h2f_lo(g0.x); a0[1] += d0 * h2f_hi(g0.x);
        a0[2] += d0 * h2f_lo(g0.y); a0[3] += d0 * h2f_hi(g0.y);
        a1[0] += d1 * h2f_lo(g1.x); a1[1] += d1 * h2f_hi(g1.x);
        a1[2] += d1 * h2f_lo(g1.y); a1[3] += d1 * h2f_hi(g1.y);
        a2[0] += d2 * h2f_lo(g2.x); a2[1] += d2 * h2f_hi(g2.x);
        a2[2] += d2 * h2f_lo(g2.y); a2[3] += d2 * h2f_hi(g2.y);
        a3[0] += d3 * h2f_lo(g3.x); a3[1] += d3 * h2f_hi(g3.x);
        a3[2] += d3 * h2f_lo(g3.y); a3[3] += d3 * h2f_hi(g3.y);
        a4[0] += d4 * h2f_lo(g4.x); a4[1] += d4 * h2f_hi(g4.x);
        a4[2] += d4 * h2f_lo(g4.y); a4[3] += d4 * h2f_hi(g4.y);
        a5[0] += d5 * h2f_lo(g5.x); a5[1] += d5 * h2f_hi(g5.x);
        a5[2] += d5 * h2f_lo(g5.y); a5[3] += d5 * h2f_hi(g5.y);
        a6[0] += d6 * h2f_lo(g6.x); a6[1] += d6 * h2f_hi(g6.x);
        a6[2] += d6 * h2f_lo(g6.y); a6[3] += d6 * h2f_hi(g6.y);
        a7[0] += d7 * h2f_lo(g7.x); a7[1] += d7 * h2f_hi(g7.x);
        a7[2] += d7 * h2f_lo(g7.y); a7[3] += d7 * h2f_hi(g7.y);
    }
    for (; t < deg; t++) {
        uint32_t j = col[base + t];
        float dj = dinv[j];
        uint2 g = *(const uint2*)(yw + (size_t)j * D_FEAT + ch);
        a0[0] += dj * h2f_lo(g.x); a0[1] += dj * h2f_hi(g.x);
        a0[2] += dj * h2f_lo(g.y); a0[3] += dj * h2f_hi(g.y);
    }
    uint2 gs = *(const uint2*)(yw + (size_t)i * D_FEAT + ch);   // +I self term
    a1[0] += di * h2f_lo(gs.x); a1[1] += di * h2f_hi(gs.x);
    a1[2] += di * h2f_lo(gs.y); a1[3] += di * h2f_hi(gs.y);
    float4v acc = ((a0 + a1) + (a2 + a3)) + ((a4 + a5) + (a6 + a7));
    *(float4v*)(out + (size_t)i * D_FEAT + ch) = di * acc;
}

// ===========================================================================
// FALLBACK PLAN (r7-proven, ~12.85 MB): global bitmap + popc + f32 gather
// ===========================================================================

__global__ void scatter_edges_fb(const int* __restrict__ ei,
                                 uint32_t* __restrict__ bitmap) {
    int e = blockIdx.x * blockDim.x + threadIdx.x;
    if (e >= E_EDGES) return;
    int s = ei[e], d = ei[E_EDGES + e];
    if ((uint32_t)s >= N_NODES || (uint32_t)d >= N_NODES) return;
    atomicOr(&bitmap[(size_t)s * ROW_STRIDE + (d >> 5)], 1u << (d & 31));
    atomicOr(&bitmap[(size_t)d * ROW_STRIDE + (s >> 5)], 1u << (s & 31));
}

__global__ void __launch_bounds__(256)
popc_dinv(const uint32_t* __restrict__ bitmap, float* __restrict__ dinv) {
    int wv = threadIdx.x >> 6, lane = threadIdx.x & 63;
    int i = blockIdx.x * 4 + wv;
    const uint32_t* rb = bitmap + (size_t)i * ROW_STRIDE;
    int pop = 0;
    #pragma unroll
    for (int k = 0; k < 5; k++) {
        int w = lane + 64 * k;
        if (w < ROW_WORDS) pop += __popc(rb[w]);
    }
    #pragma unroll
    for (int off = 32; off > 0; off >>= 1) pop += __shfl_xor(pop, off, 64);
    if (lane == 0) dinv[i] = 1.0f / sqrtf((float)(pop + 1));
}

__global__ void __launch_bounds__(256)
spmm_bitmap_fb(const uint32_t* __restrict__ bitmap, const float* __restrict__ dinv,
               const float* __restrict__ xf, float* __restrict__ agg) {
    __shared__ __align__(16) uint32_t lists[4][LIST_CAP];
    int wv = threadIdx.x >> 6, lane = threadIdx.x & 63;
    int i = blockIdx.x * 4 + wv;
    uint32_t* list = lists[wv];
    const uint32_t* rb = bitmap + (size_t)i * ROW_STRIDE;

    uint32_t wbits[5]; int tot = 0;
    #pragma unroll
    for (int k = 0; k < 5; k++) {
        int w = lane + 64 * k;
        uint32_t b = (w < ROW_WORDS) ? rb[w] : 0u;
        wbits[k] = b;
        tot += __popc(b);
    }
    int incl = tot;
    #pragma unroll
    for (int off = 1; off < 64; off <<= 1) {
        int v = __shfl_up(incl, off, 64);
        if (lane >= off) incl += v;
    }
    uint32_t p = (uint32_t)(incl - tot);
    uint32_t deg = (uint32_t)__shfl(incl, 63, 64);
    #pragma unroll
    for (int k = 0; k < 5; k++) {
        uint32_t bits = wbits[k];
        uint32_t base = (uint32_t)(lane + 64 * k) << 5;
        while (bits) {
            if (p < LIST_CAP) list[p] = base + (uint32_t)__builtin_ctz(bits);
            p++;
            bits &= bits - 1;
        }
    }
    if (deg > LIST_CAP) deg = LIST_CAP;

    float di = dinv[i];
    float4v z = {0.f, 0.f, 0.f, 0.f};
    float4v acc0 = z, acc1 = z, acc2 = z, acc3 = z;
    float4v sv = *(const float4v*)(xf + (size_t)i * D_FEAT + lane * 4);
    uint32_t t4 = deg & ~3u;
    for (uint32_t k = 0; k < t4; k += 4) {
        uint4 jv = *(const uint4*)&list[k];
        float d0 = dinv[jv.x], d1 = dinv[jv.y], d2 = dinv[jv.z], d3 = dinv[jv.w];
        float4v v0 = *(const float4v*)(xf + (size_t)jv.x * D_FEAT + lane * 4);
        float4v v1 = *(const float4v*)(xf + (size_t)jv.y * D_FEAT + lane * 4);
        float4v v2 = *(const float4v*)(xf + (size_t)jv.z * D_FEAT + lane * 4);
        float4v v3 = *(const float4v*)(xf + (size_t)jv.w * D_FEAT + lane * 4);
        acc0 += d0 * v0; acc1 += d1 * v1; acc2 += d2 * v2; acc3 += d3 * v3;
    }
    for (uint32_t k = t4; k < deg; k++) {
        uint32_t j = list[k];
        acc0 += dinv[j] * (*(const float4v*)(xf + (size_t)j * D_FEAT + lane * 4));
    }
    float4v acc = (acc0 + acc1) + (acc2 + acc3) + di * sv;
    *(float4v*)(agg + (size_t)i * D_FEAT + lane * 4) = di * acc;
}

// Fallback epilogue GEMM (in place on d_out) — r9-proven VALU version.
__global__ void __launch_bounds__(256)
gemm_valu(float* __restrict__ io, const float* __restrict__ wf) {
    __shared__ __align__(16) float a_lds[16 * D_FEAT];
    int c = threadIdx.x;
    int r0 = blockIdx.x * 16;
    for (int idx = c; idx < 16 * D_FEAT; idx += 256)
        a_lds[idx] = io[(size_t)r0 * D_FEAT + idx];
    __syncthreads();
    float acc[16];
    #pragma unroll
    for (int r = 0; r < 16; r++) acc[r] = 0.f;
    for (int k0 = 0; k0 < D_FEAT; k0 += 4) {
        float w0 = wf[(size_t)(k0 + 0) * D_FEAT + c];
        float w1 = wf[(size_t)(k0 + 1) * D_FEAT + c];
        float w2 = wf[(size_t)(k0 + 2) * D_FEAT + c];
        float w3 = wf[(size_t)(k0 + 3) * D_FEAT + c];
        #pragma unroll
        for (int r = 0; r < 16; r++) {
            float4v av = *(const float4v*)&a_lds[r * D_FEAT + k0];
            acc[r] = fmaf(av[3], w3, fmaf(av[2], w2,
                     fmaf(av[1], w1, fmaf(av[0], w0, acc[r]))));
        }
    }
    #pragma unroll
    for (int r = 0; r < 16; r++)
        io[(size_t)(r0 + r) * D_FEAT + c] = acc[r];
}

// ---------------------------------------------------------------------------
extern "C" void kernel_launch(void* const* d_in, const int* in_sizes, int n_in,
                              void* d_out, int out_size, void* d_ws, size_t ws_size,
                              hipStream_t stream) {
    const float* x  = (const float*)d_in[0];     // f32 [N, 256]
    const int*   ei = (const int*)d_in[1];       // int32 [2, E]
    const float* w  = (const float*)d_in[2];     // f32 [256, 256]
    float* out = (float*)d_out;                  // f32 [N, 256]
    uint8_t* ws = (uint8_t*)d_ws;

    // Primary layout (18.65 MB; ws ≈ 258 MB per harness poison WRITE_SIZE):
    //   cursors   @ 0          :      1,024  (250 u32, memset 1 KB)
    //   bucketbuf @ 1,024      :  8,192,000  (250 * 8192 u32, compact)
    //   row_deg   @ 8,193,024  :     40,000
    //   dinv      @ 8,233,024  :     40,000
    //   wT (f16)  @ 8,273,024  :    131,072
    //   yw (f16)  @ 8,404,096  :  5,120,000  (X @ W, gather table)
    //   col       @ 13,524,096 :  5,120,000  (10000 * 128 u32, fixed stride)
    const size_t BB_OFF   = 1024;
    const size_t RD_OFF   = 8193024;
    const size_t DI_OFF   = 8233024;
    const size_t WT_OFF   = 8273024;
    const size_t YW_OFF   = 8404096;
    const size_t COL_OFF  = 13524096;
    const size_t NEED_NEW = 18644096;
    const size_t NEED_FB  = 12840000;

    if (ws_size >= NEED_NEW) {
        uint32_t* cursors   = (uint32_t*)ws;
        uint32_t* bucketbuf = (uint32_t*)(ws + BB_OFF);
        uint32_t* row_deg   = (uint32_t*)(ws + RD_OFF);
        float*    dinv      = (float*)(ws + DI_OFF);
        _Float16* wt        = (_Float16*)(ws + WT_OFF);
        _Float16* yw        = (_Float16*)(ws + YW_OFF);
        uint32_t* col       = (uint32_t*)(ws + COL_OFF);

        hipMemsetAsync(cursors, 0, 1024, stream);
        fill_buckets<<<NBLK_E + NBLK_W, 1024, 0, stream>>>(ei, bucketbuf, cursors, w, wt);
        csr_gemm    <<<NBLK_C + NBLK_G, 1024, 0, stream>>>(bucketbuf, cursors,
                                                           row_deg, dinv, col, x, wt, yw);
        spmm_out    <<<N_NODES / 4, 256, 0, stream>>>(row_deg, dinv, col, yw, out);
    } else if (ws_size >= NEED_FB) {
        uint32_t* bitmap = (uint32_t*)ws;
        float*    dinv   = (float*)(ws + 12800000);

        hipMemsetAsync(bitmap, 0, 12800000, stream);
        scatter_edges_fb<<<(E_EDGES + 255) / 256, 256, 0, stream>>>(ei, bitmap);
        popc_dinv      <<<N_NODES / 4, 256, 0, stream>>>(bitmap, dinv);
        spmm_bitmap_fb <<<N_NODES / 4, 256, 0, stream>>>(bitmap, dinv, x, out);
        gemm_valu      <<<N_NODES / 16, 256, 0, stream>>>(out, w);
    }
    // else: ws too small for any safe plan — no-op (never observed).
}

// Round 16
// 132.069 us; speedup vs baseline: 1.0338x; 1.0338x over previous
//
#include <hip/hip_runtime.h>
#include <hip/hip_bf16.h>
#include <stdint.h>

// Problem constants (fixed by reference spec; dtypes f32/int32 verified over
// rounds 3-15 — bit-stable outputs; bounds-clamps retained as the safety net)
#define N_NODES   10000
#define D_FEAT    256
#define E_EDGES   320000
#define ROW_WORDS 313     // ceil(10000/32) bitmap words per row
#define ROW_STRIDE 320    // fallback plan: padded words per bitmap row
#define LIST_CAP  1024    // fallback plan: per-wave neighbor list capacity

// Fine-bucket CSR build (r16): 1000 buckets of 10 rows — each CSR block
// scans exactly its own ~640 entries (r15 quarter-blocks re-scanned 4x).
#define NB     1000       // buckets
#define RPB    10         // rows per bucket
#define B_CAP  1024       // entries per bucket; mean 640, sigma ~25 (15+ sigma)
#define NBLK_E 313        // edge blocks in fill_sort ((320000+1023)/1024)
#define NBLK_W 64         // wcast blocks appended to fill_sort
#define NBLK_C 1000       // csr blocks in csr_gemm (1:1 with buckets)
#define NBLK_G 625        // gemm blocks appended in csr_gemm (16 rows each)
#define COLSTR 128        // fixed col entries per row (max deg ~100 << 128)

#define LDSTR 264         // f16 LDS row stride for gemm (256 + 8 pad)

typedef __attribute__((ext_vector_type(4))) float float4v;   // 4 x f32
typedef _Float16 half8  __attribute__((ext_vector_type(8))); // 8 x f16 (4 VGPR)
typedef _Float16 half4v __attribute__((ext_vector_type(4))); // 4 x f16

__device__ __forceinline__ float h2f_lo(uint32_t u) {
    union { uint32_t u; _Float16 h[2]; } v; v.u = u; return (float)v.h[0];
}
__device__ __forceinline__ float h2f_hi(uint32_t u) {
    union { uint32_t u; _Float16 h[2]; } v; v.u = u; return (float)v.h[1];
}

// ===========================================================================
// PRIMARY PLAN (3 dispatches + 4 KB memset):
//   K1 fill_sort : 1024-bin LDS counting sort -> compact per-bucket runs
//                  (LDS-aggregated cursor atomics) + f16 W^T (fused)
//   K2 csr_gemm  : [0,1000) one-iteration bucket scan -> LDS bitmap dedup
//                  -> deg/dinv -> fixed-stride u16 CSR;
//                  [1000,1625) yw = f16(x @ W) MFMA (co-scheduled)
//   K3 spmm_out  : out_i = dinv_i*(sum dinv_j*yw_j + dinv_i*yw_i), 8-stream
// r11 lesson kept: wave-per-row in the latency-bound gather.
// ===========================================================================

// ---------------------------------------------------------------------------
// K1: blocks [0,313): counting-sorted fine-bucket fill. 1024-bin histogram,
// 10-step Hillis-Steele, coalesced run writes (r11/r13-proven pattern).
//     blocks [313,377): wT[n][k] = f16(W[k][n]) (fused, r12-proven).
// ---------------------------------------------------------------------------
__global__ void __launch_bounds__(1024)
fill_sort(const int* __restrict__ ei, uint32_t* __restrict__ bucketbuf,
          uint32_t* __restrict__ cursors,
          const float* __restrict__ w, _Float16* __restrict__ wt) {
    __shared__ uint32_t hist[1024];
    __shared__ uint32_t lofs[1024];    // inclusive scan of hist
    __shared__ uint32_t base_s[1024];
    __shared__ uint32_t stage[2048];   // also reused as f32[1024] by wcast
    __shared__ uint16_t sbkt[2048];
    int t = threadIdx.x;

    if (blockIdx.x >= NBLK_E) {        // ---- fused wcast blocks ----
        int kb = (blockIdx.x - NBLK_E) * 4;
        int k = kb + (t >> 8), n = t & 255;
        float* st = (float*)stage;     // 4 KB staging
        st[(n << 2) | (t >> 8)] = w[(size_t)k * D_FEAT + n];
        __syncthreads();
        if (t < 256) {
            half4v o = { (_Float16)st[t * 4 + 0], (_Float16)st[t * 4 + 1],
                         (_Float16)st[t * 4 + 2], (_Float16)st[t * 4 + 3] };
            *(half4v*)&wt[(size_t)t * D_FEAT + kb] = o;
        }
        return;
    }

    hist[t] = 0;
    __syncthreads();
    int e = blockIdx.x * 1024 + t;
    int b0 = -1, b1 = -1; uint32_t ent0 = 0, ent1 = 0, s0 = 0, s1 = 0;
    if (e < E_EDGES) {
        int s = ei[e], d = ei[E_EDGES + e];
        if ((uint32_t)s < N_NODES && (uint32_t)d < N_NODES) {
            b0 = s / RPB; ent0 = ((uint32_t)(s - b0 * RPB) << 14) | (uint32_t)d;
            b1 = d / RPB; ent1 = ((uint32_t)(d - b1 * RPB) << 14) | (uint32_t)s;
            s0 = atomicAdd(&hist[b0], 1u);    // LDS atomics
            s1 = atomicAdd(&hist[b1], 1u);
        }
    }
    __syncthreads();
    lofs[t] = hist[t];
    __syncthreads();
    for (int d = 1; d < 1024; d <<= 1) {             // Hillis-Steele inclusive
        uint32_t v = (t >= d) ? lofs[t - d] : 0;
        __syncthreads();
        lofs[t] += v;
        __syncthreads();
    }
    base_s[t] = hist[t] ? atomicAdd(&cursors[t], hist[t]) : 0u;
    if (b0 >= 0) {                     // stage sorted by bucket
        uint32_t p0 = lofs[b0] - hist[b0] + s0;
        stage[p0] = ent0; sbkt[p0] = (uint16_t)b0;
        uint32_t p1 = lofs[b1] - hist[b1] + s1;
        stage[p1] = ent1; sbkt[p1] = (uint16_t)b1;
    }
    __syncthreads();
    uint32_t total = lofs[1023];
    for (uint32_t idx = t; idx < total; idx += 1024) {
        uint32_t b = sbkt[idx];
        uint32_t pos = base_s[b] + (idx - (lofs[b] - hist[b]));
        if (pos < B_CAP) bucketbuf[(size_t)b * B_CAP + pos] = stage[idx];
    }
}

// ---------------------------------------------------------------------------
// K2: heterogeneous grid.
//  blocks [0,1000): bucket CSR build — scan cnt[b] (~640 <= 1024: ONE
//    strided iteration, all lanes useful), LDS bitmap dedup (12.5 KB),
//    per-row popc -> deg/dinv, expand to u16 col[gi*128 ...] (fixed stride).
//  blocks [1000,1625): yw[16 rows] = f16(x @ W): x-tile f16 in LDS, 16 waves
//    x 1 col-tile, mfma_f32_16x16x32_f16 (m89/m91 layout, r10-verified).
// ---------------------------------------------------------------------------
__global__ void __launch_bounds__(1024)
csr_gemm(const uint32_t* __restrict__ bucketbuf, const uint32_t* __restrict__ cursors,
         uint32_t* __restrict__ row_deg, float* __restrict__ dinv,
         uint16_t* __restrict__ col,
         const float* __restrict__ x, const _Float16* __restrict__ wt,
         _Float16* __restrict__ yw) {
    __shared__ __align__(16) uint32_t smem[RPB * ROW_WORDS];   // 12,520 B
    int t = threadIdx.x;

    if (blockIdx.x >= NBLK_C) {        // ---- gemm blocks ----
        _Float16* a_lds = (_Float16*)smem;             // 16*264 f16 = 8448 B
        int r0 = (blockIdx.x - NBLK_C) * 16;
        int row = t >> 6, c4 = (t & 63) * 4;           // 1024 thr = 16x64 f4
        float4v xv = *(const float4v*)(x + (size_t)(r0 + row) * D_FEAT + c4);
        half4v h = { (_Float16)xv[0], (_Float16)xv[1],
                     (_Float16)xv[2], (_Float16)xv[3] };
        *(half4v*)&a_lds[row * LDSTR + c4] = h;
        __syncthreads();
        int wv = t >> 6, lane = t & 63;
        int quad = lane >> 4, r = lane & 15;
        int ct = wv;                                   // 16 waves = 16 col tiles
        const _Float16* pb = wt + (size_t)(ct * 16 + r) * D_FEAT + quad * 8;
        float4v acc = {0.f, 0.f, 0.f, 0.f};
        #pragma unroll
        for (int kk = 0; kk < D_FEAT; kk += 32) {
            half8 a = *(const half8*)&a_lds[r * LDSTR + kk + quad * 8];
            half8 b = *(const half8*)(pb + kk);
            acc = __builtin_amdgcn_mfma_f32_16x16x32_f16(a, b, acc, 0, 0, 0);
        }
        int colg = ct * 16 + r;
        #pragma unroll
        for (int u = 0; u < 4; u++)
            yw[(size_t)(r0 + quad * 4 + u) * D_FEAT + colg] = (_Float16)acc[u];
        return;
    }

    // ---- csr blocks (1:1 with buckets) ----
    uint32_t* bm = smem;                               // 10*313 words
    int b = blockIdx.x;
    for (int i = t; i < RPB * ROW_WORDS; i += 1024) bm[i] = 0;
    __syncthreads();
    uint32_t cnt = min(cursors[b], (uint32_t)B_CAP);
    const uint32_t* bb = bucketbuf + (size_t)b * B_CAP;
    for (uint32_t i = t; i < cnt; i += 1024) {         // <= 1 iteration
        uint32_t ent = bb[i];
        uint32_t lr = ent >> 14, d = ent & 0x3FFFu;
        atomicOr(&bm[lr * ROW_WORDS + (d >> 5)], 1u << (d & 31));
    }
    __syncthreads();
    int wv = t >> 6, lane = t & 63;                    // 16 waves, 10 rows
    if (wv < RPB) {
        int r = wv;
        int gi = b * RPB + r;
        uint32_t wb[5]; int tot = 0;
        #pragma unroll
        for (int k = 0; k < 5; k++) {
            int w = lane + 64 * k;
            uint32_t v = (w < ROW_WORDS) ? bm[r * ROW_WORDS + w] : 0u;
            wb[k] = v; tot += __popc(v);
        }
        int incl = tot;
        #pragma unroll
        for (int off = 1; off < 64; off <<= 1) {
            int v = __shfl_up(incl, off, 64);
            if (lane >= off) incl += v;
        }
        uint32_t total = (uint32_t)__shfl(incl, 63, 64);
        if (lane == 0) {
            row_deg[gi] = min(total, (uint32_t)COLSTR);
            dinv[gi]    = 1.0f / sqrtf((float)(total + 1u));  // +1 = the eye
        }
        uint32_t p = (uint32_t)(incl - tot);
        #pragma unroll
        for (int k = 0; k < 5; k++) {
            uint32_t bits = wb[k];
            uint32_t cbase = (uint32_t)(lane + 64 * k) << 5;
            while (bits) {
                if (p < COLSTR)
                    col[(size_t)gi * COLSTR + p] =
                        (uint16_t)(cbase + (uint32_t)__builtin_ctz(bits));
                p++;
                bits &= bits - 1;
            }
        }
    }
}

// ---------------------------------------------------------------------------
// K3: final gather straight into d_out (f32). Wave-per-row (10000 waves),
// 8 independent gather streams (r13-proven). u16 col: 8 indices per 16B
// wave-uniform load. yw is UNSCALED X@W (out = S·(X·W) reassociation).
// ---------------------------------------------------------------------------
__global__ void __launch_bounds__(256)
spmm_out(const uint32_t* __restrict__ row_deg, const float* __restrict__ dinv,
         const uint16_t* __restrict__ col, const _Float16* __restrict__ ywp,
         float* __restrict__ out) {
    const uint16_t* yw = (const uint16_t*)ywp;
    int wv = threadIdx.x >> 6, lane = threadIdx.x & 63;
    int i = blockIdx.x * 4 + wv;
    uint32_t base = (uint32_t)i * COLSTR;
    uint32_t deg = min(row_deg[i], (uint32_t)COLSTR);
    float di = dinv[i];
    float4v z = {0.f, 0.f, 0.f, 0.f};
    float4v a0 = z, a1 = z, a2 = z, a3 = z, a4 = z, a5 = z, a6 = z, a7 = z;
    size_t ch = (size_t)lane * 4;
    uint32_t t8 = deg & ~7u;
    uint32_t t = 0;
    for (; t < t8; t += 8) {
        uint4 cv = *(const uint4*)&col[base + t];        // 8 u16, wave-uniform
        uint32_t j0 = cv.x & 0xffffu, j1 = cv.x >> 16;
        uint32_t j2 = cv.y & 0xffffu, j3 = cv.y >> 16;
        uint32_t j4 = cv.z & 0xffffu, j5 = cv.z >> 16;
        uint32_t j6 = cv.w & 0xffffu, j7 = cv.w >> 16;
        float d0 = dinv[j0], d1 = dinv[j1], d2 = dinv[j2], d3 = dinv[j3];
        float d4 = dinv[j4], d5 = dinv[j5], d6 = dinv[j6], d7 = dinv[j7];
        uint2 g0 = *(const uint2*)(yw + (size_t)j0 * D_FEAT + ch);
        uint2 g1 = *(const uint2*)(yw + (size_t)j1 * D_FEAT + ch);
        uint2 g2 = *(const uint2*)(yw + (size_t)j2 * D_FEAT + ch);
        uint2 g3 = *(const uint2*)(yw + (size_t)j3 * D_FEAT + ch);
        uint2 g4 = *(const uint2*)(yw + (size_t)j4 * D_FEAT + ch);
        uint2 g5 = *(const uint2*)(yw + (size_t)j5 * D_FEAT + ch);
        uint2 g6 = *(const uint2*)(yw + (size_t)j6 * D_FEAT + ch);
        uint2 g7 = *(const uint2*)(yw + (size_t)j7 * D_FEAT + ch);
        a0[0] += d0 * h2f_lo(g0.x); a0[1] += d0 * h2f_hi(g0.x);
        a0[2] += d0 * h2f_lo(g0.y); a0[3] += d0 * h2f_hi(g0.y);
        a1[0] += d1 * h2f_lo(g1.x); a1[1] += d1 * h2f_hi(g1.x);
        a1[2] += d1 * h2f_lo(g1.y); a1[3] += d1 * h2f_hi(g1.y);
        a2[0] += d2 * h2f_lo(g2.x); a2[1] += d2 * h2f_hi(g2.x);
        a2[2] += d2 * h2f_lo(g2.y); a2[3] += d2 * h2f_hi(g2.y);
        a3[0] += d3 * h2f_lo(g3.x); a3[1] += d3 * h2f_hi(g3.x);
        a3[2] += d3 * h2f_lo(g3.y); a3[3] += d3 * h2f_hi(g3.y);
        a4[0] += d4 * h2f_lo(g4.x); a4[1] += d4 * h2f_hi(g4.x);
        a4[2] += d4 * h2f_lo(g4.y); a4[3] += d4 * h2f_hi(g4.y);
        a5[0] += d5 * h2f_lo(g5.x); a5[1] += d5 * h2f_hi(g5.x);
        a5[2] += d5 * h2f_lo(g5.y); a5[3] += d5 * h2f_hi(g5.y);
        a6[0] += d6 * h2f_lo(g6.x); a6[1] += d6 * h2f_hi(g6.x);
        a6[2] += d6 * h2f_lo(g6.y); a6[3] += d6 * h2f_hi(g6.y);
        a7[0] += d7 * h2f_lo(g7.x); a7[1] += d7 * h2f_hi(g7.x);
        a7[2] += d7 * h2f_lo(g7.y); a7[3] += d7 * h2f_hi(g7.y);
    }
    for (; t < deg; t++) {
        uint32_t j = col[base + t];
        float dj = dinv[j];
        uint2 g = *(const uint2*)(yw + (size_t)j * D_FEAT + ch);
        a0[0] += dj * h2f_lo(g.x); a0[1] += dj * h2f_hi(g.x);
        a0[2] += dj * h2f_lo(g.y); a0[3] += dj * h2f_hi(g.y);
    }
    uint2 gs = *(const uint2*)(yw + (size_t)i * D_FEAT + ch);   // +I self term
    a1[0] += di * h2f_lo(gs.x); a1[1] += di * h2f_hi(gs.x);
    a1[2] += di * h2f_lo(gs.y); a1[3] += di * h2f_hi(gs.y);
    float4v acc = ((a0 + a1) + (a2 + a3)) + ((a4 + a5) + (a6 + a7));
    *(float4v*)(out + (size_t)i * D_FEAT + ch) = di * acc;
}

// ===========================================================================
// FALLBACK PLAN (r7-proven, ~12.85 MB): global bitmap + popc + f32 gather
// ===========================================================================

__global__ void scatter_edges_fb(const int* __restrict__ ei,
                                 uint32_t* __restrict__ bitmap) {
    int e = blockIdx.x * blockDim.x + threadIdx.x;
    if (e >= E_EDGES) return;
    int s = ei[e], d = ei[E_EDGES + e];
    if ((uint32_t)s >= N_NODES || (uint32_t)d >= N_NODES) return;
    atomicOr(&bitmap[(size_t)s * ROW_STRIDE + (d >> 5)], 1u << (d & 31));
    atomicOr(&bitmap[(size_t)d * ROW_STRIDE + (s >> 5)], 1u << (s & 31));
}

__global__ void __launch_bounds__(256)
popc_dinv(const uint32_t* __restrict__ bitmap, float* __restrict__ dinv) {
    int wv = threadIdx.x >> 6, lane = threadIdx.x & 63;
    int i = blockIdx.x * 4 + wv;
    const uint32_t* rb = bitmap + (size_t)i * ROW_STRIDE;
    int pop = 0;
    #pragma unroll
    for (int k = 0; k < 5; k++) {
        int w = lane + 64 * k;
        if (w < ROW_WORDS) pop += __popc(rb[w]);
    }
    #pragma unroll
    for (int off = 32; off > 0; off >>= 1) pop += __shfl_xor(pop, off, 64);
    if (lane == 0) dinv[i] = 1.0f / sqrtf((float)(pop + 1));
}

__global__ void __launch_bounds__(256)
spmm_bitmap_fb(const uint32_t* __restrict__ bitmap, const float* __restrict__ dinv,
               const float* __restrict__ xf, float* __restrict__ agg) {
    __shared__ __align__(16) uint32_t lists[4][LIST_CAP];
    int wv = threadIdx.x >> 6, lane = threadIdx.x & 63;
    int i = blockIdx.x * 4 + wv;
    uint32_t* list = lists[wv];
    const uint32_t* rb = bitmap + (size_t)i * ROW_STRIDE;

    uint32_t wbits[5]; int tot = 0;
    #pragma unroll
    for (int k = 0; k < 5; k++) {
        int w = lane + 64 * k;
        uint32_t b = (w < ROW_WORDS) ? rb[w] : 0u;
        wbits[k] = b;
        tot += __popc(b);
    }
    int incl = tot;
    #pragma unroll
    for (int off = 1; off < 64; off <<= 1) {
        int v = __shfl_up(incl, off, 64);
        if (lane >= off) incl += v;
    }
    uint32_t p = (uint32_t)(incl - tot);
    uint32_t deg = (uint32_t)__shfl(incl, 63, 64);
    #pragma unroll
    for (int k = 0; k < 5; k++) {
        uint32_t bits = wbits[k];
        uint32_t base = (uint32_t)(lane + 64 * k) << 5;
        while (bits) {
            if (p < LIST_CAP) list[p] = base + (uint32_t)__builtin_ctz(bits);
            p++;
            bits &= bits - 1;
        }
    }
    if (deg > LIST_CAP) deg = LIST_CAP;

    float di = dinv[i];
    float4v z = {0.f, 0.f, 0.f, 0.f};
    float4v acc0 = z, acc1 = z, acc2 = z, acc3 = z;
    float4v sv = *(const float4v*)(xf + (size_t)i * D_FEAT + lane * 4);
    uint32_t t4 = deg & ~3u;
    for (uint32_t k = 0; k < t4; k += 4) {
        uint4 jv = *(const uint4*)&list[k];
        float d0 = dinv[jv.x], d1 = dinv[jv.y], d2 = dinv[jv.z], d3 = dinv[jv.w];
        float4v v0 = *(const float4v*)(xf + (size_t)jv.x * D_FEAT + lane * 4);
        float4v v1 = *(const float4v*)(xf + (size_t)jv.y * D_FEAT + lane * 4);
        float4v v2 = *(const float4v*)(xf + (size_t)jv.z * D_FEAT + lane * 4);
        float4v v3 = *(const float4v*)(xf + (size_t)jv.w * D_FEAT + lane * 4);
        acc0 += d0 * v0; acc1 += d1 * v1; acc2 += d2 * v2; acc3 += d3 * v3;
    }
    for (uint32_t k = t4; k < deg; k++) {
        uint32_t j = list[k];
        acc0 += dinv[j] * (*(const float4v*)(xf + (size_t)j * D_FEAT + lane * 4));
    }
    float4v acc = (acc0 + acc1) + (acc2 + acc3) + di * sv;
    *(float4v*)(agg + (size_t)i * D_FEAT + lane * 4) = di * acc;
}

// Fallback epilogue GEMM (in place on d_out) — r9-proven VALU version.
__global__ void __launch_bounds__(256)
gemm_valu(float* __restrict__ io, const float* __restrict__ wf) {
    __shared__ __align__(16) float a_lds[16 * D_FEAT];
    int c = threadIdx.x;
    int r0 = blockIdx.x * 16;
    for (int idx = c; idx < 16 * D_FEAT; idx += 256)
        a_lds[idx] = io[(size_t)r0 * D_FEAT + idx];
    __syncthreads();
    float acc[16];
    #pragma unroll
    for (int r = 0; r < 16; r++) acc[r] = 0.f;
    for (int k0 = 0; k0 < D_FEAT; k0 += 4) {
        float w0 = wf[(size_t)(k0 + 0) * D_FEAT + c];
        float w1 = wf[(size_t)(k0 + 1) * D_FEAT + c];
        float w2 = wf[(size_t)(k0 + 2) * D_FEAT + c];
        float w3 = wf[(size_t)(k0 + 3) * D_FEAT + c];
        #pragma unroll
        for (int r = 0; r < 16; r++) {
            float4v av = *(const float4v*)&a_lds[r * D_FEAT + k0];
            acc[r] = fmaf(av[3], w3, fmaf(av[2], w2,
                     fmaf(av[1], w1, fmaf(av[0], w0, acc[r]))));
        }
    }
    #pragma unroll
    for (int r = 0; r < 16; r++)
        io[(size_t)(r0 + r) * D_FEAT + c] = acc[r];
}

// ---------------------------------------------------------------------------
extern "C" void kernel_launch(void* const* d_in, const int* in_sizes, int n_in,
                              void* d_out, int out_size, void* d_ws, size_t ws_size,
                              hipStream_t stream) {
    const float* x  = (const float*)d_in[0];     // f32 [N, 256]
    const int*   ei = (const int*)d_in[1];       // int32 [2, E]
    const float* w  = (const float*)d_in[2];     // f32 [256, 256]
    float* out = (float*)d_out;                  // f32 [N, 256]
    uint8_t* ws = (uint8_t*)d_ws;

    // Primary layout (12.0 MB):
    //   cursors   @ 0          :      4,096  (1000 u32, memset 4 KB)
    //   bucketbuf @ 4,096      :  4,096,000  (1000 * 1024 u32, compact)
    //   row_deg   @ 4,100,096  :     40,000
    //   dinv      @ 4,140,096  :     40,000
    //   wT (f16)  @ 4,180,096  :    131,072
    //   yw (f16)  @ 4,311,168  :  5,120,000  (X @ W, gather table)
    //   col (u16) @ 9,431,168  :  2,560,000  (10000 * 128 u16, fixed stride)
    const size_t BB_OFF   = 4096;
    const size_t RD_OFF   = 4100096;
    const size_t DI_OFF   = 4140096;
    const size_t WT_OFF   = 4180096;
    const size_t YW_OFF   = 4311168;
    const size_t COL_OFF  = 9431168;
    const size_t NEED_NEW = 11991168;
    const size_t NEED_FB  = 12840000;

    if (ws_size >= NEED_NEW) {
        uint32_t* cursors   = (uint32_t*)ws;
        uint32_t* bucketbuf = (uint32_t*)(ws + BB_OFF);
        uint32_t* row_deg   = (uint32_t*)(ws + RD_OFF);
        float*    dinv      = (float*)(ws + DI_OFF);
        _Float16* wt        = (_Float16*)(ws + WT_OFF);
        _Float16* yw        = (_Float16*)(ws + YW_OFF);
        uint16_t* col       = (uint16_t*)(ws + COL_OFF);

        hipMemsetAsync(cursors, 0, 4096, stream);
        fill_sort<<<NBLK_E + NBLK_W, 1024, 0, stream>>>(ei, bucketbuf, cursors, w, wt);
        csr_gemm <<<NBLK_C + NBLK_G, 1024, 0, stream>>>(bucketbuf, cursors,
                                                        row_deg, dinv, col, x, wt, yw);
        spmm_out <<<N_NODES / 4, 256, 0, stream>>>(row_deg, dinv, col, yw, out);
    } else if (ws_size >= NEED_FB) {
        uint32_t* bitmap = (uint32_t*)ws;
        float*    dinv   = (float*)(ws + 12800000);

        hipMemsetAsync(bitmap, 0, 12800000, stream);
        scatter_edges_fb<<<(E_EDGES + 255) / 256, 256, 0, stream>>>(ei, bitmap);
        popc_dinv      <<<N_NODES / 4, 256, 0, stream>>>(bitmap, dinv);
        spmm_bitmap_fb <<<N_NODES / 4, 256, 0, stream>>>(bitmap, dinv, x, out);
        gemm_valu      <<<N_NODES / 16, 256, 0, stream>>>(out, w);
    }
    // else: ws too small for any safe plan — no-op (never observed).
}